// Round 2
// baseline (105.809 us; speedup 1.0000x reference)
//
#include <hip/hip_runtime.h>

#define B_ 8
#define C_ 256
#define S_ 2048
#define T_ (B_*S_)      // 16384 tokens
#define RN_ 8

typedef short s8v __attribute__((ext_vector_type(8)));
typedef short s4v __attribute__((ext_vector_type(4)));
typedef float f4v __attribute__((ext_vector_type(4)));

__device__ inline short f2b(float f){            // fp32 -> bf16 RNE
  unsigned u = __builtin_bit_cast(unsigned, f);
  unsigned r = (u + 0x7FFFu + ((u >> 16) & 1u)) >> 16;
  return (short)r;
}
__device__ inline float b2f(short s){
  unsigned u = ((unsigned)(unsigned short)s) << 16;
  return __builtin_bit_cast(float, u);
}

// K1: x (B,C,S) fp32 -> xT (token-major: b*S+s, c) bf16. 64x64 LDS tile transpose.
__global__ __launch_bounds__(256) void k_tx(const float* __restrict__ x, short* __restrict__ xT){
  int bid = blockIdx.x;
  int b  = bid >> 7;           // 128 tiles per b (4 c-tiles x 32 s-tiles)
  int ct = (bid >> 5) & 3;
  int st = bid & 31;
  __shared__ float tile[64][65];
  int tid = threadIdx.x;
  const float* xb = x + b*(C_*S_);
  #pragma unroll
  for (int it = 0; it < 4; ++it){
    int row = it*16 + (tid >> 4);       // c-local
    int s4  = tid & 15;
    float4 v = *(const float4*)(xb + (ct*64 + row)*S_ + st*64 + s4*4);
    tile[row][s4*4+0] = v.x; tile[row][s4*4+1] = v.y;
    tile[row][s4*4+2] = v.z; tile[row][s4*4+3] = v.w;
  }
  __syncthreads();
  #pragma unroll
  for (int it = 0; it < 4; ++it){
    int srow = it*16 + (tid >> 4);      // s-local
    int c4   = tid & 15;
    s4v o;
    o[0] = f2b(tile[c4*4+0][srow]); o[1] = f2b(tile[c4*4+1][srow]);
    o[2] = f2b(tile[c4*4+2][srow]); o[3] = f2b(tile[c4*4+3][srow]);
    *(s4v*)(xT + (b*S_ + st*64 + srow)*C_ + ct*64 + c4*4) = o;
  }
}

// K2: weight (R,C,M) fp32 -> wT (R,M,C) bf16
__global__ __launch_bounds__(256) void k_tw(const float* __restrict__ wgt, short* __restrict__ wT){
  int bid = blockIdx.x;
  int r  = bid >> 4;
  int ct = (bid >> 2) & 3;
  int mt = bid & 3;
  __shared__ float tile[64][65];
  int tid = threadIdx.x;
  const float* wb = wgt + r*(C_*256);
  #pragma unroll
  for (int it = 0; it < 4; ++it){
    int row = it*16 + (tid >> 4);       // c-local
    int m4  = tid & 15;
    float4 v = *(const float4*)(wb + (ct*64 + row)*256 + mt*64 + m4*4);
    tile[row][m4*4+0] = v.x; tile[row][m4*4+1] = v.y;
    tile[row][m4*4+2] = v.z; tile[row][m4*4+3] = v.w;
  }
  __syncthreads();
  #pragma unroll
  for (int it = 0; it < 4; ++it){
    int mrow = it*16 + (tid >> 4);      // m-local
    int c4   = tid & 15;
    s4v o;
    o[0] = f2b(tile[c4*4+0][mrow]); o[1] = f2b(tile[c4*4+1][mrow]);
    o[2] = f2b(tile[c4*4+2][mrow]); o[3] = f2b(tile[c4*4+3][mrow]);
    *(s4v*)(wT + r*65536 + (mt*64 + mrow)*256 + ct*64 + c4*4) = o;
  }
}

// K3: bucket tokens by expert (order within bucket irrelevant -> deterministic output)
__global__ __launch_bounds__(256) void k_bucket(const int* __restrict__ idx,
                                                int* __restrict__ counts, int* __restrict__ bucket){
  int t = blockIdx.x*256 + threadIdx.x;
  int e = idx[t] & 7;                 // int32 per harness ("integer -> const int*")
  int pos = atomicAdd(counts + e, 1);
  bucket[e*T_ + pos] = t;
}

// K4: grouped GEMM per (expert, 64-token tile). yT written IN-PLACE over xT (safe: each
// token row is read once, by its owning block, into LDS before its epilogue store).
__global__ __launch_bounds__(256) void k_gemm(const short* __restrict__ xT, const short* __restrict__ wT,
                                              const float* __restrict__ bias, const int* __restrict__ counts,
                                              const int* __restrict__ bucket, short* __restrict__ yT){
  int e    = blockIdx.x >> 8;
  int tile = blockIdx.x & 255;
  int cnt  = counts[e];
  if (tile*64 >= cnt) return;

  __shared__ short Xg[64*256];   // 32KB, XOR-swizzled (row stride 512B -> 16-way conflict w/o swizzle)
  __shared__ short Wc[256*64];   // 32KB, (m,k) layout, XOR-swizzled
  __shared__ float biasS[256];
  __shared__ int   toks[64];

  int tid  = threadIdx.x;
  int lane = tid & 63;
  int wv   = tid >> 6;
  int l15  = lane & 15, lq = lane >> 4;

  if (tid < 64){
    int i = tile*64 + tid;
    toks[tid] = (i < cnt) ? bucket[e*T_ + i] : -1;
  }
  biasS[tid] = bias[e*256 + tid];
  __syncthreads();

  char* XgB = (char*)Xg;
  char* WcB = (char*)Wc;
  // stage A: 64 token rows x 256 c (bf16), rows gathered via bucket
  #pragma unroll
  for (int it = 0; it < 8; ++it){
    int q = it*256 + tid;
    int row = q >> 5, c8 = q & 31;
    int tok = toks[row]; if (tok < 0) tok = 0;    // dup row0: harmless, stores guarded
    s8v v = *(const s8v*)(xT + tok*256 + c8*8);
    *(s8v*)(XgB + ((row*512 + c8*16) ^ ((row & 7) << 4))) = v;
  }

  f4v acc[4][4];
  #pragma unroll
  for (int i = 0; i < 4; ++i)
    #pragma unroll
    for (int j = 0; j < 4; ++j)
      acc[i][j] = (f4v){0.f, 0.f, 0.f, 0.f};

  const short* wTe = wT + e*65536;
  for (int kc0 = 0; kc0 < 256; kc0 += 64){
    __syncthreads();                              // protect Wc reuse (and publish Xg on iter 0)
    #pragma unroll
    for (int it = 0; it < 8; ++it){
      int q = it*256 + tid;
      int m = q >> 3, k8 = q & 7;
      s8v v = *(const s8v*)(wTe + m*256 + kc0 + k8*8);
      *(s8v*)(WcB + ((m*128 + k8*16) ^ ((m & 7) << 4))) = v;
    }
    __syncthreads();
    #pragma unroll
    for (int kk = 0; kk < 64; kk += 32){
      s8v af[4], bfv[4];
      #pragma unroll
      for (int mi = 0; mi < 4; ++mi){
        int row = mi*16 + l15;                    // A: row = lane&15, k = (lane>>4)*8 + i
        af[mi] = *(const s8v*)(XgB + ((row*512 + (kc0 + kk + lq*8)*2) ^ ((row & 7) << 4)));
      }
      #pragma unroll
      for (int ni = 0; ni < 4; ++ni){
        int m = wv*64 + ni*16 + l15;              // B: col = lane&15, k = (lane>>4)*8 + i
        bfv[ni] = *(const s8v*)(WcB + ((m*128 + (kk + lq*8)*2) ^ ((m & 7) << 4)));
      }
      #pragma unroll
      for (int mi = 0; mi < 4; ++mi)
        #pragma unroll
        for (int ni = 0; ni < 4; ++ni)
          acc[mi][ni] = __builtin_amdgcn_mfma_f32_16x16x32_bf16(af[mi], bfv[ni], acc[mi][ni], 0, 0, 0);
    }
  }

  // epilogue: D col = lane&15, row = (lane>>4)*4 + reg [m89]; residual from Xg LDS (maxR==C)
  #pragma unroll
  for (int mi = 0; mi < 4; ++mi){
    #pragma unroll
    for (int r = 0; r < 4; ++r){
      int row = mi*16 + lq*4 + r;
      int tok = toks[row];
      if (tok < 0) continue;
      #pragma unroll
      for (int ni = 0; ni < 4; ++ni){
        int m = wv*64 + ni*16 + l15;
        float xv  = b2f(*(const short*)(XgB + ((row*512 + m*2) ^ ((row & 7) << 4))));
        float val = acc[mi][ni][r] + xv + biasS[m];
        yT[tok*256 + m] = f2b(val);
      }
    }
  }
}

// K5: yT token-major bf16 -> out (B,C,S) fp32 with mask fused; also writes mask output
__global__ __launch_bounds__(256) void k_final(const short* __restrict__ yT, const int* __restrict__ idx,
                                               const int* __restrict__ rate_choice,
                                               float* __restrict__ outx, float* __restrict__ outm){
  int bid = blockIdx.x;
  int b  = bid >> 7;
  int ct = (bid >> 5) & 3;
  int st = bid & 31;
  __shared__ float tile[64][65];
  __shared__ int rateS[64];
  int tid = threadIdx.x;
  if (tid < 64) rateS[tid] = rate_choice[idx[b*S_ + st*64 + tid] & 7];
  #pragma unroll
  for (int it = 0; it < 4; ++it){
    int srow = it*16 + (tid >> 4);
    int c4   = tid & 15;
    s4v v = *(const s4v*)(yT + (b*S_ + st*64 + srow)*256 + ct*64 + c4*4);
    tile[c4*4+0][srow] = b2f(v[0]); tile[c4*4+1][srow] = b2f(v[1]);
    tile[c4*4+2][srow] = b2f(v[2]); tile[c4*4+3][srow] = b2f(v[3]);
  }
  __syncthreads();
  #pragma unroll
  for (int it = 0; it < 16; ++it){
    int cl = it*4 + (tid >> 6);
    int sl = tid & 63;
    int cg = ct*64 + cl;
    float v = tile[cl][sl];
    bool keep = cg < rateS[sl];
    int off = b*(C_*S_) + cg*S_ + st*64 + sl;
    outx[off] = keep ? v : 0.0f;
    outm[off] = keep ? 1.0f : 0.0f;
  }
}

__global__ __launch_bounds__(256) void k_idx_f(const int* __restrict__ idx, float* __restrict__ out){
  int t = blockIdx.x*256 + threadIdx.x;
  out[t] = (float)idx[t];
}

extern "C" void kernel_launch(void* const* d_in, const int* in_sizes, int n_in,
                              void* d_out, int out_size, void* d_ws, size_t ws_size,
                              hipStream_t stream){
  const float* x    = (const float*)d_in[0];
  const int*   idx  = (const int*)d_in[1];     // int32 (harness: integer -> const int*)
  const float* wgt  = (const float*)d_in[2];
  const float* bias = (const float*)d_in[3];
  const int*   rate = (const int*)d_in[4];

  char* ws = (char*)d_ws;
  short* xT     = (short*)ws;                 // 8 MB bf16 token-major; becomes yT in-place
  short* wT     = (short*)(ws + 8388608);     // 1 MB bf16 (R,M,C)
  int*   bucket = (int*)  (ws + 9437184);     // 512 KB
  int*   counts = (int*)  (ws + 9961472);     // 32 B

  float* outx = (float*)d_out;
  float* outm = outx + (B_*C_*S_);

  hipMemsetAsync(counts, 0, 32, stream);
  k_tx    <<<1024, 256, 0, stream>>>(x, xT);
  k_tw    <<<128,  256, 0, stream>>>(wgt, wT);
  k_bucket<<<T_/256, 256, 0, stream>>>(idx, counts, bucket);
  k_gemm  <<<RN_*256, 256, 0, stream>>>(xT, wT, bias, counts, bucket, xT /*in-place yT*/);
  k_final <<<1024, 256, 0, stream>>>(xT, idx, rate, outx, outm);

  k_idx_f<<<T_/256, 256, 0, stream>>>(idx, outx + 2*B_*C_*S_);
}

// Round 3
// 44.094 us; speedup vs baseline: 2.3996x; 2.3996x over previous
//
#include <hip/hip_runtime.h>

#define B_ 8
#define C_ 256
#define S_ 2048
#define T_ (B_*S_)      // 16384 tokens
#define RN_ 8

typedef short s8v __attribute__((ext_vector_type(8)));
typedef short s4v __attribute__((ext_vector_type(4)));
typedef float f4v __attribute__((ext_vector_type(4)));

__device__ inline short f2b(float f){            // fp32 -> bf16 RNE
  unsigned u = __builtin_bit_cast(unsigned, f);
  unsigned r = (u + 0x7FFFu + ((u >> 16) & 1u)) >> 16;
  return (short)r;
}
__device__ inline float b2f(short s){
  unsigned u = ((unsigned)(unsigned short)s) << 16;
  return __builtin_bit_cast(float, u);
}

// K1: x (B,C,S) fp32 -> xT (token-major: b*S+s, c) bf16. 64x64 LDS tile transpose.
__global__ __launch_bounds__(256) void k_tx(const float* __restrict__ x, short* __restrict__ xT){
  int bid = blockIdx.x;
  int b  = bid >> 7;           // 128 tiles per b (4 c-tiles x 32 s-tiles)
  int ct = (bid >> 5) & 3;
  int st = bid & 31;
  __shared__ float tile[64][65];
  int tid = threadIdx.x;
  const float* xb = x + b*(C_*S_);
  #pragma unroll
  for (int it = 0; it < 4; ++it){
    int row = it*16 + (tid >> 4);       // c-local
    int s4  = tid & 15;
    float4 v = *(const float4*)(xb + (ct*64 + row)*S_ + st*64 + s4*4);
    tile[row][s4*4+0] = v.x; tile[row][s4*4+1] = v.y;
    tile[row][s4*4+2] = v.z; tile[row][s4*4+3] = v.w;
  }
  __syncthreads();
  #pragma unroll
  for (int it = 0; it < 4; ++it){
    int srow = it*16 + (tid >> 4);      // s-local
    int c4   = tid & 15;
    s4v o;
    o[0] = f2b(tile[c4*4+0][srow]); o[1] = f2b(tile[c4*4+1][srow]);
    o[2] = f2b(tile[c4*4+2][srow]); o[3] = f2b(tile[c4*4+3][srow]);
    *(s4v*)(xT + (b*S_ + st*64 + srow)*C_ + ct*64 + c4*4) = o;
  }
}

// K2: weight (R,C,M) fp32 -> wT (R,M,C) bf16
__global__ __launch_bounds__(256) void k_tw(const float* __restrict__ wgt, short* __restrict__ wT){
  int bid = blockIdx.x;
  int r  = bid >> 4;
  int ct = (bid >> 2) & 3;
  int mt = bid & 3;
  __shared__ float tile[64][65];
  int tid = threadIdx.x;
  const float* wb = wgt + r*(C_*256);
  #pragma unroll
  for (int it = 0; it < 4; ++it){
    int row = it*16 + (tid >> 4);       // c-local
    int m4  = tid & 15;
    float4 v = *(const float4*)(wb + (ct*64 + row)*256 + mt*64 + m4*4);
    tile[row][m4*4+0] = v.x; tile[row][m4*4+1] = v.y;
    tile[row][m4*4+2] = v.z; tile[row][m4*4+3] = v.w;
  }
  __syncthreads();
  #pragma unroll
  for (int it = 0; it < 4; ++it){
    int mrow = it*16 + (tid >> 4);      // m-local
    int c4   = tid & 15;
    s4v o;
    o[0] = f2b(tile[c4*4+0][mrow]); o[1] = f2b(tile[c4*4+1][mrow]);
    o[2] = f2b(tile[c4*4+2][mrow]); o[3] = f2b(tile[c4*4+3][mrow]);
    *(s4v*)(wT + r*65536 + (mt*64 + mrow)*256 + ct*64 + c4*4) = o;
  }
}

// K3: bucket tokens by expert. Per-block LDS aggregation: 256 LDS atomics + <=8 global
// atomics per block (vs 16384 global atomics on 8 addrs = 63us of serialization in R2).
// Bucket order varies run-to-run but every token's GEMM result is slot-independent ->
// d_out bit-identical. Also fuses the indexes->float passthrough output.
__global__ __launch_bounds__(256) void k_bucket(const int* __restrict__ idx,
                                                int* __restrict__ counts, int* __restrict__ bucket,
                                                float* __restrict__ idx_out){
  __shared__ int lcount[8];
  __shared__ int lbase[8];
  int tid = threadIdx.x;
  int t   = blockIdx.x*256 + tid;
  if (tid < 8) lcount[tid] = 0;
  __syncthreads();
  int ei = idx[t];
  int e  = ei & 7;
  int lp = atomicAdd(&lcount[e], 1);       // LDS atomic: block-local rank
  __syncthreads();
  if (tid < 8){
    int c = lcount[tid];
    lbase[tid] = c ? atomicAdd(counts + tid, c) : 0;   // one global atomic per expert per block
  }
  __syncthreads();
  bucket[e*T_ + lbase[e] + lp] = t;
  idx_out[t] = (float)ei;
}

// K4: grouped GEMM per (expert, 64-token tile). yT written IN-PLACE over xT (safe: each
// token row is read once, by its owning block, into LDS before its epilogue store).
__global__ __launch_bounds__(256) void k_gemm(const short* __restrict__ xT, const short* __restrict__ wT,
                                              const float* __restrict__ bias, const int* __restrict__ counts,
                                              const int* __restrict__ bucket, short* __restrict__ yT){
  int e    = blockIdx.x >> 8;
  int tile = blockIdx.x & 255;
  int cnt  = counts[e];
  if (tile*64 >= cnt) return;

  __shared__ short Xg[64*256];   // 32KB, XOR-swizzled (row stride 512B -> 16-way conflict w/o swizzle)
  __shared__ short Wc[256*64];   // 32KB, (m,k) layout, XOR-swizzled
  __shared__ float biasS[256];
  __shared__ int   toks[64];

  int tid  = threadIdx.x;
  int lane = tid & 63;
  int wv   = tid >> 6;
  int l15  = lane & 15, lq = lane >> 4;

  if (tid < 64){
    int i = tile*64 + tid;
    toks[tid] = (i < cnt) ? bucket[e*T_ + i] : -1;
  }
  biasS[tid] = bias[e*256 + tid];
  __syncthreads();

  char* XgB = (char*)Xg;
  char* WcB = (char*)Wc;
  // stage A: 64 token rows x 256 c (bf16), rows gathered via bucket
  #pragma unroll
  for (int it = 0; it < 8; ++it){
    int q = it*256 + tid;
    int row = q >> 5, c8 = q & 31;
    int tok = toks[row]; if (tok < 0) tok = 0;    // dup row0: harmless, stores guarded
    s8v v = *(const s8v*)(xT + tok*256 + c8*8);
    *(s8v*)(XgB + ((row*512 + c8*16) ^ ((row & 7) << 4))) = v;
  }

  f4v acc[4][4];
  #pragma unroll
  for (int i = 0; i < 4; ++i)
    #pragma unroll
    for (int j = 0; j < 4; ++j)
      acc[i][j] = (f4v){0.f, 0.f, 0.f, 0.f};

  const short* wTe = wT + e*65536;
  for (int kc0 = 0; kc0 < 256; kc0 += 64){
    __syncthreads();                              // protect Wc reuse (and publish Xg on iter 0)
    #pragma unroll
    for (int it = 0; it < 8; ++it){
      int q = it*256 + tid;
      int m = q >> 3, k8 = q & 7;
      s8v v = *(const s8v*)(wTe + m*256 + kc0 + k8*8);
      *(s8v*)(WcB + ((m*128 + k8*16) ^ ((m & 7) << 4))) = v;
    }
    __syncthreads();
    #pragma unroll
    for (int kk = 0; kk < 64; kk += 32){
      s8v af[4], bfv[4];
      #pragma unroll
      for (int mi = 0; mi < 4; ++mi){
        int row = mi*16 + l15;                    // A: row = lane&15, k = (lane>>4)*8 + i
        af[mi] = *(const s8v*)(XgB + ((row*512 + (kc0 + kk + lq*8)*2) ^ ((row & 7) << 4)));
      }
      #pragma unroll
      for (int ni = 0; ni < 4; ++ni){
        int m = wv*64 + ni*16 + l15;              // B: col = lane&15, k = (lane>>4)*8 + i
        bfv[ni] = *(const s8v*)(WcB + ((m*128 + (kk + lq*8)*2) ^ ((m & 7) << 4)));
      }
      #pragma unroll
      for (int mi = 0; mi < 4; ++mi)
        #pragma unroll
        for (int ni = 0; ni < 4; ++ni)
          acc[mi][ni] = __builtin_amdgcn_mfma_f32_16x16x32_bf16(af[mi], bfv[ni], acc[mi][ni], 0, 0, 0);
    }
  }

  // epilogue: D col = lane&15, row = (lane>>4)*4 + reg [m89]; residual from Xg LDS (maxR==C)
  #pragma unroll
  for (int mi = 0; mi < 4; ++mi){
    #pragma unroll
    for (int r = 0; r < 4; ++r){
      int row = mi*16 + lq*4 + r;
      int tok = toks[row];
      if (tok < 0) continue;
      #pragma unroll
      for (int ni = 0; ni < 4; ++ni){
        int m = wv*64 + ni*16 + l15;
        float xv  = b2f(*(const short*)(XgB + ((row*512 + m*2) ^ ((row & 7) << 4))));
        float val = acc[mi][ni][r] + xv + biasS[m];
        yT[tok*256 + m] = f2b(val);
      }
    }
  }
}

// K5: yT token-major bf16 -> out (B,C,S) fp32 with mask fused; also writes mask output
__global__ __launch_bounds__(256) void k_final(const short* __restrict__ yT, const int* __restrict__ idx,
                                               const int* __restrict__ rate_choice,
                                               float* __restrict__ outx, float* __restrict__ outm){
  int bid = blockIdx.x;
  int b  = bid >> 7;
  int ct = (bid >> 5) & 3;
  int st = bid & 31;
  __shared__ float tile[64][65];
  __shared__ int rateS[64];
  int tid = threadIdx.x;
  if (tid < 64) rateS[tid] = rate_choice[idx[b*S_ + st*64 + tid] & 7];
  #pragma unroll
  for (int it = 0; it < 4; ++it){
    int srow = it*16 + (tid >> 4);
    int c4   = tid & 15;
    s4v v = *(const s4v*)(yT + (b*S_ + st*64 + srow)*256 + ct*64 + c4*4);
    tile[c4*4+0][srow] = b2f(v[0]); tile[c4*4+1][srow] = b2f(v[1]);
    tile[c4*4+2][srow] = b2f(v[2]); tile[c4*4+3][srow] = b2f(v[3]);
  }
  __syncthreads();
  #pragma unroll
  for (int it = 0; it < 16; ++it){
    int cl = it*4 + (tid >> 6);
    int sl = tid & 63;
    int cg = ct*64 + cl;
    float v = tile[cl][sl];
    bool keep = cg < rateS[sl];
    int off = b*(C_*S_) + cg*S_ + st*64 + sl;
    outx[off] = keep ? v : 0.0f;
    outm[off] = keep ? 1.0f : 0.0f;
  }
}

extern "C" void kernel_launch(void* const* d_in, const int* in_sizes, int n_in,
                              void* d_out, int out_size, void* d_ws, size_t ws_size,
                              hipStream_t stream){
  const float* x    = (const float*)d_in[0];
  const int*   idx  = (const int*)d_in[1];     // int32 (harness: integer -> const int*)
  const float* wgt  = (const float*)d_in[2];
  const float* bias = (const float*)d_in[3];
  const int*   rate = (const int*)d_in[4];

  char* ws = (char*)d_ws;
  short* xT     = (short*)ws;                 // 8 MB bf16 token-major; becomes yT in-place
  short* wT     = (short*)(ws + 8388608);     // 1 MB bf16 (R,M,C)
  int*   bucket = (int*)  (ws + 9437184);     // 512 KB
  int*   counts = (int*)  (ws + 9961472);     // 32 B

  float* outx = (float*)d_out;
  float* outm = outx + (B_*C_*S_);

  hipMemsetAsync(counts, 0, 32, stream);
  k_tx    <<<1024, 256, 0, stream>>>(x, xT);
  k_tw    <<<128,  256, 0, stream>>>(wgt, wT);
  k_bucket<<<T_/256, 256, 0, stream>>>(idx, counts, bucket, outx + 2*B_*C_*S_);
  k_gemm  <<<RN_*256, 256, 0, stream>>>(xT, wT, bias, counts, bucket, xT /*in-place yT*/);
  k_final <<<1024, 256, 0, stream>>>(xT, idx, rate, outx, outm);
}